// Round 3
// baseline (806.236 us; speedup 1.0000x reference)
//
#include <hip/hip_runtime.h>
#include <hip/hip_bf16.h>

// Music-Transformer RelativeGlobalAttention, MI355X round 2.
// B=2, T=2048, D=512, H=8, hd=64, ED=512, EV=388. fp32 compute.
// R2: runtime dtype detection (fp32 vs bf16 harness I/O) via the deterministic
// causal mask's first word. All kernels take dual load paths; final store
// writes fp32 or bf16 per the detected flag. E is canonicalized to bf16 in ws.

#define B_ 2
#define T_ 2048
#define DM_ 512
#define H_ 8
#define HD_ 64
#define ED_ 512
#define EV_ 388
#define BT_ (B_ * T_)

__device__ __forceinline__ float bflo(unsigned int p) {
  union { unsigned int i; float f; } v; v.i = p << 16; return v.f;
}
__device__ __forceinline__ float bfhi(unsigned int p) {
  union { unsigned int i; float f; } v; v.i = p & 0xffff0000u; return v.f;
}
__device__ __forceinline__ float bfs(unsigned short s) {
  union { unsigned int i; float f; } v; v.i = ((unsigned int)s) << 16; return v.f;
}
__device__ __forceinline__ unsigned short f2bf(float f) {
  __hip_bfloat16 h = __float2bfloat16(f);
  union { __hip_bfloat16 h; unsigned short u; } v; v.h = h; return v.u;
}

// ---------------------------------------------------------------------------
// K0: dtype detect. mask[0:2] = {1,0}: fp32 word0 = 0x3F800000, bf16-packed
// word0 = 0x00003F80. flag: 0 = fp32, 1 = bf16.
// ---------------------------------------------------------------------------
__global__ void detect_kernel(const unsigned int* __restrict__ mask,
                              int* __restrict__ flag) {
  *flag = (mask[0] == 0x3F800000u) ? 0 : 1;
}

// K0b: canonicalize E -> bf16 buffer (copy if already bf16, downcast if fp32).
__global__ __launch_bounds__(256) void convE_kernel(
    const void* __restrict__ src, unsigned short* __restrict__ dst,
    const int* __restrict__ flag) {
  const int i0 = (blockIdx.x * 256 + threadIdx.x) * 4;  // n = 1048576 exact
  if (*flag) {
    *(uint2*)&dst[i0] = *(const uint2*)((const unsigned short*)src + i0);
  } else {
    const float4 f = *(const float4*)((const float*)src + i0);
    dst[i0 + 0] = f2bf(f.x); dst[i0 + 1] = f2bf(f.y);
    dst[i0 + 2] = f2bf(f.z); dst[i0 + 3] = f2bf(f.w);
  }
}

// ---------------------------------------------------------------------------
// K1: qh/kh/vh = x @ W + b   (x: [BT,512], W: [512,64] -> fp32 out)
// grid (BT/16, 3), block 256. Each block: 16 rows; each thread: 4 rows x 1 col.
// ---------------------------------------------------------------------------
__global__ __launch_bounds__(256) void proj_kernel(
    const void* __restrict__ qg, const void* __restrict__ kg,
    const void* __restrict__ vg,
    const void* __restrict__ Wq, const void* __restrict__ bq,
    const void* __restrict__ Wk, const void* __restrict__ bk,
    const void* __restrict__ Wv, const void* __restrict__ bv,
    float* __restrict__ qh, float* __restrict__ kh, float* __restrict__ vh,
    const int* __restrict__ flag) {
  __shared__ float xs[16][DM_ + 4];
  const int sel = blockIdx.y;
  const void* x  = (sel == 0) ? qg : (sel == 1) ? kg : vg;
  const void* W  = (sel == 0) ? Wq : (sel == 1) ? Wk : Wv;
  const void* bb = (sel == 0) ? bq : (sel == 1) ? bk : bv;
  float* out = (sel == 0) ? qh : (sel == 1) ? kh : vh;

  const int tid = threadIdx.x;
  const int row0 = blockIdx.x * 16;
  const bool isbf = (*flag != 0);

  if (isbf) {
    const unsigned short* xp = (const unsigned short*)x;
#pragma unroll
    for (int it = 0; it < 4; ++it) {
      int idx = tid + it * 256;
      int r = idx >> 6;
      int c = (idx & 63) * 8;
      uint4 u = *(const uint4*)(xp + (size_t)(row0 + r) * DM_ + c);
      float* dst = &xs[r][c];
      dst[0] = bflo(u.x); dst[1] = bfhi(u.x); dst[2] = bflo(u.y); dst[3] = bfhi(u.y);
      dst[4] = bflo(u.z); dst[5] = bfhi(u.z); dst[6] = bflo(u.w); dst[7] = bfhi(u.w);
    }
  } else {
    const float* xp = (const float*)x;
#pragma unroll
    for (int it = 0; it < 8; ++it) {
      int idx = tid + it * 256;          // 2048 float4 over 16x512
      int r = idx >> 7;
      int c = (idx & 127) * 4;
      *(float4*)&xs[r][c] = *(const float4*)(xp + (size_t)(row0 + r) * DM_ + c);
    }
  }
  __syncthreads();

  const int c = tid & 63;
  const int rg = tid >> 6;
  float a0 = 0.f, a1 = 0.f, a2 = 0.f, a3 = 0.f;
  if (isbf) {
    const unsigned short* Wp = (const unsigned short*)W;
#pragma unroll 8
    for (int d = 0; d < DM_; ++d) {
      float w = bfs(Wp[d * HD_ + c]);
      a0 = fmaf(xs[rg * 4 + 0][d], w, a0);
      a1 = fmaf(xs[rg * 4 + 1][d], w, a1);
      a2 = fmaf(xs[rg * 4 + 2][d], w, a2);
      a3 = fmaf(xs[rg * 4 + 3][d], w, a3);
    }
  } else {
    const float* Wp = (const float*)W;
#pragma unroll 8
    for (int d = 0; d < DM_; ++d) {
      float w = Wp[d * HD_ + c];
      a0 = fmaf(xs[rg * 4 + 0][d], w, a0);
      a1 = fmaf(xs[rg * 4 + 1][d], w, a1);
      a2 = fmaf(xs[rg * 4 + 2][d], w, a2);
      a3 = fmaf(xs[rg * 4 + 3][d], w, a3);
    }
  }
  const float bias = isbf ? bfs(((const unsigned short*)bb)[c])
                          : ((const float*)bb)[c];
  size_t base = (size_t)(row0 + rg * 4) * HD_ + c;
  out[base           ] = a0 + bias;
  out[base + 1 * HD_ ] = a1 + bias;
  out[base + 2 * HD_ ] = a2 + bias;
  out[base + 3 * HD_ ] = a3 + bias;
}

// ---------------------------------------------------------------------------
// K2: fused causal attention with Music-Transformer relative bias.
// Block = one (head h, batch b, 64-query tile t0). Online softmax over
// 64-key tiles s0 <= t0. S[t,s] = (qh[t].kh[s] + qh[t].E[h, T-1+s-t]) / 8.
// E comes from the canonical bf16 ws buffer. LDS: sS/sEb overlay, 55040 B.
// ---------------------------------------------------------------------------
__global__ __launch_bounds__(256) void attn_kernel(
    const float* __restrict__ qh, const float* __restrict__ kh,
    const float* __restrict__ vh, const unsigned short* __restrict__ E,
    float* __restrict__ ctx) {
  __shared__ float sQ[64][68];
  __shared__ float sKV[64][68];
  __shared__ __align__(16) unsigned char sUnion[128 * 72 * 2];  // 18432 B
  __shared__ float sRed[64][4];
  __shared__ float sM[64], sL[64], sAlpha[64];
  float (*sS)[68] = (float (*)[68])sUnion;                     // 64x68 fp32
  unsigned short (*sEb)[72] = (unsigned short (*)[72])sUnion;  // 128x72 bf16

  const int r = blockIdx.x;
  int ti, hb;
  if (r < 256) { ti = 31 - (r >> 4); hb = r & 15; }
  else         { ti = (r - 256) >> 4; hb = r & 15; }
  const int h = hb >> 1;
  const int b = hb & 1;
  const int t0 = ti * 64;

  const int tid = threadIdx.x;
  const int tx = tid & 15;
  const int ty = tid >> 4;

  {
    const float4* src = (const float4*)(qh + (size_t)(b * T_ + t0) * HD_);
#pragma unroll
    for (int it = 0; it < 4; ++it) {
      int idx = tid + it * 256;
      *(float4*)&sQ[idx >> 4][(idx & 15) * 4] = src[idx];
    }
  }
  if (tid < 64) { sM[tid] = -3.0e38f; sL[tid] = 0.0f; }
  float ctxa[4][4];
#pragma unroll
  for (int i = 0; i < 4; ++i)
#pragma unroll
    for (int j = 0; j < 4; ++j) ctxa[i][j] = 0.f;

  const unsigned short* Eh = E + (size_t)h * T_ * HD_;
  const int nk = ti + 1;

  for (int kt = 0; kt < nk; ++kt) {
    const int s0 = kt * 64;
    {
      const float4* src = (const float4*)(kh + (size_t)(b * T_ + s0) * HD_);
#pragma unroll
      for (int it = 0; it < 4; ++it) {
        int idx = tid + it * 256;
        *(float4*)&sKV[idx >> 4][(idx & 15) * 4] = src[idx];
      }
    }
    const int rb = (T_ - 64) + s0 - t0;  // band row 0 <-> s-t = -63
    {
#pragma unroll
      for (int it = 0; it < 4; ++it) {
        int idx = tid + it * 256;
        int row = idx >> 3;
        int col = (idx & 7) * 8;
        int gr = rb + row;
        if (gr > T_ - 1) gr = T_ - 1;   // masked rows anyway
        uint4 u = *(const uint4*)(Eh + (size_t)gr * HD_ + col);
        *(uint4*)&sEb[row][col] = u;
      }
    }
    __syncthreads();  // S1

    float accS[4][4];
#pragma unroll
    for (int i = 0; i < 4; ++i)
#pragma unroll
      for (int j = 0; j < 4; ++j) accS[i][j] = 0.f;

    for (int d = 0; d < HD_; d += 4) {
      float4 qv[4], kv[4];
#pragma unroll
      for (int i = 0; i < 4; ++i) qv[i] = *(const float4*)&sQ[ty + 16 * i][d];
#pragma unroll
      for (int j = 0; j < 4; ++j) kv[j] = *(const float4*)&sKV[tx + 16 * j][d];
      float ev[7][4];
#pragma unroll
      for (int dg = 0; dg < 7; ++dg) {
        int bidx = (tx - ty) + 16 * dg + 15;   // = (s-t)+63
        uint2 u = *(const uint2*)&sEb[bidx][d];
        ev[dg][0] = bflo(u.x); ev[dg][1] = bfhi(u.x);
        ev[dg][2] = bflo(u.y); ev[dg][3] = bfhi(u.y);
      }
#pragma unroll
      for (int i = 0; i < 4; ++i) {
#pragma unroll
        for (int j = 0; j < 4; ++j) {
          const float* e = ev[j - i + 3];
          float a = accS[i][j];
          a = fmaf(qv[i].x, kv[j].x, a); a = fmaf(qv[i].y, kv[j].y, a);
          a = fmaf(qv[i].z, kv[j].z, a); a = fmaf(qv[i].w, kv[j].w, a);
          a = fmaf(qv[i].x, e[0], a);    a = fmaf(qv[i].y, e[1], a);
          a = fmaf(qv[i].z, e[2], a);    a = fmaf(qv[i].w, e[3], a);
          accS[i][j] = a;
        }
      }
    }
    __syncthreads();  // S1b — sEb reads done before sS overwrites union

#pragma unroll
    for (int i = 0; i < 4; ++i) {
      int tl = ty + 16 * i;
#pragma unroll
      for (int j = 0; j < 4; ++j) {
        int sl = tx + 16 * j;
        float sv = ((s0 + sl) <= (t0 + tl)) ? accS[i][j] * 0.125f : -1.0e30f;
        accS[i][j] = sv;
        sS[tl][sl] = sv;
      }
    }
    __syncthreads();  // S2

    {
      const float4* src = (const float4*)(vh + (size_t)(b * T_ + s0) * HD_);
#pragma unroll
      for (int it = 0; it < 4; ++it) {
        int idx = tid + it * 256;
        *(float4*)&sKV[idx >> 4][(idx & 15) * 4] = src[idx];
      }
    }
    {
      int rr = tid >> 2, qq = tid & 3;
      const float* rp = &sS[rr][qq * 16];
      float4 x0 = *(const float4*)(rp + 0);
      float4 x1 = *(const float4*)(rp + 4);
      float4 x2 = *(const float4*)(rp + 8);
      float4 x3 = *(const float4*)(rp + 12);
      float m = fmaxf(fmaxf(fmaxf(x0.x, x0.y), fmaxf(x0.z, x0.w)),
                      fmaxf(fmaxf(x1.x, x1.y), fmaxf(x1.z, x1.w)));
      m = fmaxf(m, fmaxf(fmaxf(fmaxf(x2.x, x2.y), fmaxf(x2.z, x2.w)),
                         fmaxf(fmaxf(x3.x, x3.y), fmaxf(x3.z, x3.w))));
      sRed[rr][qq] = m;
    }
    __syncthreads();  // S3
    if (tid < 64) {
      float mt = fmaxf(fmaxf(sRed[tid][0], sRed[tid][1]),
                       fmaxf(sRed[tid][2], sRed[tid][3]));
      float mo = sM[tid];
      float mn = fmaxf(mo, mt);
      sAlpha[tid] = __expf(mo - mn);
      sM[tid] = mn;
    }
    __syncthreads();  // S4
#pragma unroll
    for (int i = 0; i < 4; ++i) {
      int tl = ty + 16 * i;
      float mrow = sM[tl];
#pragma unroll
      for (int j = 0; j < 4; ++j) {
        sS[tl][tx + 16 * j] = __expf(accS[i][j] - mrow);
      }
    }
    __syncthreads();  // S5
    {
      int rr = tid >> 2, qq = tid & 3;
      const float* rp = &sS[rr][qq * 16];
      float4 x0 = *(const float4*)(rp + 0);
      float4 x1 = *(const float4*)(rp + 4);
      float4 x2 = *(const float4*)(rp + 8);
      float4 x3 = *(const float4*)(rp + 12);
      float s = (x0.x + x0.y + x0.z + x0.w) + (x1.x + x1.y + x1.z + x1.w)
              + (x2.x + x2.y + x2.z + x2.w) + (x3.x + x3.y + x3.z + x3.w);
      sRed[rr][qq] = s;
    }
#pragma unroll
    for (int i = 0; i < 4; ++i) {
      float a = sAlpha[ty + 16 * i];
#pragma unroll
      for (int j = 0; j < 4; ++j) ctxa[i][j] *= a;
    }
    for (int s = 0; s < 64; s += 4) {
      float4 v0 = *(const float4*)&sKV[s + 0][tx * 4];
      float4 v1 = *(const float4*)&sKV[s + 1][tx * 4];
      float4 v2 = *(const float4*)&sKV[s + 2][tx * 4];
      float4 v3 = *(const float4*)&sKV[s + 3][tx * 4];
#pragma unroll
      for (int i = 0; i < 4; ++i) {
        float4 pp = *(const float4*)&sS[ty + 16 * i][s];
        ctxa[i][0] = fmaf(pp.x, v0.x, fmaf(pp.y, v1.x, fmaf(pp.z, v2.x, fmaf(pp.w, v3.x, ctxa[i][0]))));
        ctxa[i][1] = fmaf(pp.x, v0.y, fmaf(pp.y, v1.y, fmaf(pp.z, v2.y, fmaf(pp.w, v3.y, ctxa[i][1]))));
        ctxa[i][2] = fmaf(pp.x, v0.z, fmaf(pp.y, v1.z, fmaf(pp.z, v2.z, fmaf(pp.w, v3.z, ctxa[i][2]))));
        ctxa[i][3] = fmaf(pp.x, v0.w, fmaf(pp.y, v1.w, fmaf(pp.z, v2.w, fmaf(pp.w, v3.w, ctxa[i][3]))));
      }
    }
    __syncthreads();  // S6
    if (tid < 64) {
      float ssum = sRed[tid][0] + sRed[tid][1] + sRed[tid][2] + sRed[tid][3];
      sL[tid] = sL[tid] * sAlpha[tid] + ssum;
    }
  }
  __syncthreads();
#pragma unroll
  for (int i = 0; i < 4; ++i) {
    int tl = ty + 16 * i;
    float inv = 1.0f / sL[tl];
    float4 o;
    o.x = ctxa[i][0] * inv; o.y = ctxa[i][1] * inv;
    o.z = ctxa[i][2] * inv; o.w = ctxa[i][3] * inv;
    *(float4*)&ctx[(size_t)(b * T_ + t0 + tl) * DM_ + h * HD_ + tx * 4] = o;
  }
}

// ---------------------------------------------------------------------------
// K3: C = act(A @ W + bias). A fp32 [4096,512], W [512,N] (dtype per flag).
// RELU=1 -> fp32 out (h1);  RELU=0 -> d_out per flag (bf16 or fp32).
// ---------------------------------------------------------------------------
template <int RELU>
__global__ __launch_bounds__(256) void mlp_kernel(
    const float* __restrict__ A, const void* __restrict__ W,
    const void* __restrict__ bias, float* __restrict__ outF,
    void* __restrict__ outD, int N, const int* __restrict__ flag) {
  __shared__ float sA[128][36];
  __shared__ float sW[64][36];  // transposed: [n][k]
  const int tid = threadIdx.x;
  const int tx = tid & 15;
  const int ty = tid >> 4;
  const int row0 = blockIdx.x * 128;
  const int n0 = blockIdx.y * 64;
  const bool isbf = (*flag != 0);

  float acc[8][4];
#pragma unroll
  for (int i = 0; i < 8; ++i)
#pragma unroll
    for (int j = 0; j < 4; ++j) acc[i][j] = 0.f;

  for (int k0 = 0; k0 < DM_; k0 += 32) {
#pragma unroll
    for (int it = 0; it < 4; ++it) {
      int idx = tid + it * 256;
      int rr = idx >> 3;
      int cc = (idx & 7) * 4;
      *(float4*)&sA[rr][cc] = *(const float4*)&A[(size_t)(row0 + rr) * DM_ + k0 + cc];
    }
    {
      int kk = tid >> 3;
      int c0 = (tid & 7) * 8;
      if (isbf) {
        const unsigned short* wr = (const unsigned short*)W + (size_t)(k0 + kk) * N;
#pragma unroll
        for (int e = 0; e < 8; ++e) {
          int n = n0 + c0 + e;
          if (n > N - 1) n = N - 1;
          sW[c0 + e][kk] = bfs(wr[n]);
        }
      } else {
        const float* wr = (const float*)W + (size_t)(k0 + kk) * N;
#pragma unroll
        for (int e = 0; e < 8; ++e) {
          int n = n0 + c0 + e;
          if (n > N - 1) n = N - 1;
          sW[c0 + e][kk] = wr[n];
        }
      }
    }
    __syncthreads();
#pragma unroll
    for (int kk = 0; kk < 32; kk += 4) {
      float4 av[8], wv[4];
#pragma unroll
      for (int i = 0; i < 8; ++i) av[i] = *(const float4*)&sA[ty + 16 * i][kk];
#pragma unroll
      for (int j = 0; j < 4; ++j) wv[j] = *(const float4*)&sW[tx + 16 * j][kk];
#pragma unroll
      for (int i = 0; i < 8; ++i) {
#pragma unroll
        for (int j = 0; j < 4; ++j) {
          float a = acc[i][j];
          a = fmaf(av[i].x, wv[j].x, a);
          a = fmaf(av[i].y, wv[j].y, a);
          a = fmaf(av[i].z, wv[j].z, a);
          a = fmaf(av[i].w, wv[j].w, a);
          acc[i][j] = a;
        }
      }
    }
    __syncthreads();
  }

#pragma unroll
  for (int j = 0; j < 4; ++j) {
    int n = n0 + tx + 16 * j;
    float bb;
    if (n < N) bb = isbf ? bfs(((const unsigned short*)bias)[n])
                         : ((const float*)bias)[n];
    else bb = 0.f;
#pragma unroll
    for (int i = 0; i < 8; ++i) {
      float v = acc[i][j] + bb;
      int row = row0 + ty + 16 * i;
      if (RELU) {
        v = fmaxf(v, 0.f);
        outF[(size_t)row * N + n] = v;           // N=512 here: n always < N
      } else if (n < N) {
        if (isbf) ((unsigned short*)outD)[(size_t)row * N + n] = f2bf(v);
        else      ((float*)outD)[(size_t)row * N + n] = v;
      }
    }
  }
}

// ---------------------------------------------------------------------------
extern "C" void kernel_launch(void* const* d_in, const int* in_sizes, int n_in,
                              void* d_out, int out_size, void* d_ws, size_t ws_size,
                              hipStream_t stream) {
  const void* v  = d_in[0];
  const void* k  = d_in[1];
  const void* q  = d_in[2];
  const void* mask = d_in[3];
  const void* Wq = d_in[4];
  const void* bq = d_in[5];
  const void* Wk = d_in[6];
  const void* bk = d_in[7];
  const void* Wv = d_in[8];
  const void* bv = d_in[9];
  const void* E  = d_in[10];
  const void* Wo = d_in[11];
  const void* bo = d_in[12];
  const void* Wl = d_in[13];
  const void* bl = d_in[14];

  char* wsb = (char*)d_ws;
  int* flag = (int*)wsb;                                     // 256 B reserved
  unsigned short* E_c = (unsigned short*)(wsb + 256);        // 1M bf16 = 2 MB
  float* qh  = (float*)(wsb + 256 + 2097152);                // [BT,64]
  float* kh  = qh  + (size_t)BT_ * HD_;
  float* vh  = kh  + (size_t)BT_ * HD_;
  float* ctx = vh  + (size_t)BT_ * HD_;                      // [BT,512]
  float* h1  = ctx + (size_t)BT_ * DM_;                      // [BT,512]

  detect_kernel<<<1, 1, 0, stream>>>((const unsigned int*)mask, flag);
  convE_kernel<<<dim3(1024), 256, 0, stream>>>(E, E_c, flag);
  proj_kernel<<<dim3(BT_ / 16, 3), 256, 0, stream>>>(
      q, k, v, Wq, bq, Wk, bk, Wv, bv, qh, kh, vh, flag);
  attn_kernel<<<dim3(512), 256, 0, stream>>>(qh, kh, vh, E_c, ctx);
  mlp_kernel<1><<<dim3(BT_ / 128, ED_ / 64), 256, 0, stream>>>(
      ctx, Wo, bo, h1, nullptr, ED_, flag);
  mlp_kernel<0><<<dim3(BT_ / 128, (EV_ + 63) / 64), 256, 0, stream>>>(
      h1, Wl, bl, nullptr, d_out, EV_, flag);
}

// Round 4
// 285.802 us; speedup vs baseline: 2.8210x; 2.8210x over previous
//
#include <hip/hip_runtime.h>
#include <hip/hip_bf16.h>

// Music-Transformer RelativeGlobalAttention, MI355X round 3: full MFMA port.
// B=2, T=2048, D=512, H=8, hd=64, ED=512, EV=388. fp32 I/O (runtime-detected),
// bf16 MFMA compute with fp32 accumulation.

#define B_ 2
#define T_ 2048
#define DM_ 512
#define H_ 8
#define HD_ 64
#define ED_ 512
#define EV_ 388
#define BT_ (B_ * T_)

typedef __attribute__((ext_vector_type(8))) short short8;   // 8 bf16 = 4 VGPR
typedef __attribute__((ext_vector_type(4))) float floatx4;  // MFMA C/D

#define MFMA(a, b, c) __builtin_amdgcn_mfma_f32_16x16x32_bf16((a), (b), (c), 0, 0, 0)

__device__ __forceinline__ float bfs(unsigned short s) {
  union { unsigned int i; float f; } v; v.i = ((unsigned int)s) << 16; return v.f;
}
__device__ __forceinline__ unsigned short f2bf(float f) {
  __hip_bfloat16 h = __float2bfloat16(f);
  union { __hip_bfloat16 h; unsigned short u; } v; v.h = h; return v.u;
}
__device__ __forceinline__ float ldf(const void* p, int i, bool isbf) {
  return isbf ? bfs(((const unsigned short*)p)[i]) : ((const float*)p)[i];
}

// ---------------------------------------------------------------------------
// K0: dtype detect. mask[0]=1.0f: fp32 word = 0x3F800000; bf16-packed differs.
// ---------------------------------------------------------------------------
__global__ void detect_kernel(const unsigned int* __restrict__ mask,
                              int* __restrict__ flag) {
  *flag = (mask[0] == 0x3F800000u) ? 0 : 1;
}

// K0b: canonicalize E -> bf16 [8][2048][64].
__global__ __launch_bounds__(256) void convE_kernel(
    const void* __restrict__ src, unsigned short* __restrict__ dst,
    const int* __restrict__ flag) {
  const int i0 = (blockIdx.x * 256 + threadIdx.x) * 4;  // 1,048,576 elems exact
  if (*flag) {
    *(uint2*)&dst[i0] = *(const uint2*)((const unsigned short*)src + i0);
  } else {
    const float4 f = *(const float4*)((const float*)src + i0);
    dst[i0 + 0] = f2bf(f.x); dst[i0 + 1] = f2bf(f.y);
    dst[i0 + 2] = f2bf(f.z); dst[i0 + 3] = f2bf(f.w);
  }
}

// K0c: weight transpose + bf16: src [512][N] (dtype per flag) -> dst [Npad][512]
// bf16 row-major, zero-padded rows n>=N. grid (ceil(Npad/256), 64), K=512.
__global__ __launch_bounds__(256) void convT_kernel(
    const void* __restrict__ src, unsigned short* __restrict__ dst,
    int N, int Npad, const int* __restrict__ flag) {
  const int n = blockIdx.x * 256 + threadIdx.x;
  if (n >= Npad) return;
  const int k0 = blockIdx.y * 8;
  const bool isbf = (*flag != 0);
  unsigned short vv[8];
#pragma unroll
  for (int j = 0; j < 8; ++j) {
    if (n >= N) vv[j] = 0;
    else if (isbf) vv[j] = ((const unsigned short*)src)[(size_t)(k0 + j) * N + n];
    else vv[j] = f2bf(((const float*)src)[(size_t)(k0 + j) * N + n]);
  }
  *(uint4*)&dst[(size_t)n * DM_ + k0] = *(uint4*)vv;
}

// ---------------------------------------------------------------------------
// K1: projections via MFMA. grid (4096/128, 3). Block: 128 rows x 64 cols.
// sel 0/1: out row-major bf16 [4096][64] (qh/kh). sel 2: out transposed
// vh_t [B][64][2048] bf16 (B-operand layout for PV).
// ---------------------------------------------------------------------------
__global__ __launch_bounds__(256) void gemm_proj(
    const void* __restrict__ xq, const void* __restrict__ xk,
    const void* __restrict__ xv,
    const unsigned short* __restrict__ WqT, const unsigned short* __restrict__ WkT,
    const unsigned short* __restrict__ WvT,
    const void* __restrict__ bq, const void* __restrict__ bk,
    const void* __restrict__ bv,
    unsigned short* __restrict__ oq, unsigned short* __restrict__ ok,
    unsigned short* __restrict__ ovt, const int* __restrict__ flag) {
  __shared__ __align__(16) short sA[128][72];
  __shared__ __align__(16) short sW[64][72];
  const int sel = blockIdx.y;
  const void* x = (sel == 0) ? xq : (sel == 1) ? xk : xv;
  const unsigned short* WT = (sel == 0) ? WqT : (sel == 1) ? WkT : WvT;
  const void* bias = (sel == 0) ? bq : (sel == 1) ? bk : bv;

  const int tid = threadIdx.x;
  const int w = tid >> 6;
  const int lane = tid & 63;
  const int q_ = lane >> 4;
  const int n_ = lane & 15;
  const int row0 = blockIdx.x * 128;
  const bool isbf = (*flag != 0);

  floatx4 acc[2][4];
#pragma unroll
  for (int i = 0; i < 2; ++i)
#pragma unroll
    for (int j = 0; j < 4; ++j) acc[i][j] = (floatx4){0.f, 0.f, 0.f, 0.f};

  for (int k0 = 0; k0 < DM_; k0 += 64) {
    if (isbf) {
#pragma unroll
      for (int it = 0; it < 4; ++it) {
        int idx = tid + it * 256;
        int rr = idx >> 3, cc = (idx & 7) * 8;
        *(uint4*)&sA[rr][cc] =
            *(const uint4*)((const unsigned short*)x + (size_t)(row0 + rr) * DM_ + k0 + cc);
      }
    } else {
#pragma unroll
      for (int it = 0; it < 8; ++it) {
        int idx = tid + it * 256;
        int rr = idx >> 4, cc = (idx & 15) * 4;
        float4 f = *(const float4*)((const float*)x + (size_t)(row0 + rr) * DM_ + k0 + cc);
        unsigned short p[4] = {f2bf(f.x), f2bf(f.y), f2bf(f.z), f2bf(f.w)};
        *(uint2*)&sA[rr][cc] = *(uint2*)p;
      }
    }
#pragma unroll
    for (int it = 0; it < 2; ++it) {
      int idx = tid + it * 256;
      int rr = idx >> 3, cc = (idx & 7) * 8;
      *(uint4*)&sW[rr][cc] = *(const uint4*)(WT + (size_t)rr * DM_ + k0 + cc);
    }
    __syncthreads();

    short8 a[2][2];
#pragma unroll
    for (int mm = 0; mm < 2; ++mm) {
      a[mm][0] = *(const short8*)&sA[32 * w + 16 * mm + n_][8 * q_];
      a[mm][1] = *(const short8*)&sA[32 * w + 16 * mm + n_][32 + 8 * q_];
    }
#pragma unroll
    for (int nb = 0; nb < 4; ++nb) {
      short8 b0 = *(const short8*)&sW[16 * nb + n_][8 * q_];
      short8 b1 = *(const short8*)&sW[16 * nb + n_][32 + 8 * q_];
#pragma unroll
      for (int mm = 0; mm < 2; ++mm) {
        acc[mm][nb] = MFMA(a[mm][0], b0, acc[mm][nb]);
        acc[mm][nb] = MFMA(a[mm][1], b1, acc[mm][nb]);
      }
    }
    __syncthreads();
  }

#pragma unroll
  for (int nb = 0; nb < 4; ++nb) {
    const int col = 16 * nb + n_;
    const float bb = ldf(bias, col, isbf);
#pragma unroll
    for (int mm = 0; mm < 2; ++mm) {
#pragma unroll
      for (int r = 0; r < 4; ++r) {
        int row = row0 + 32 * w + 16 * mm + 4 * q_ + r;
        unsigned short val = f2bf(acc[mm][nb][r] + bb);
        if (sel < 2) {
          unsigned short* o = (sel == 0) ? oq : ok;
          o[(size_t)row * HD_ + col] = val;
        } else {
          int b = row >> 11, s = row & 2047;
          ovt[(((size_t)(b * HD_ + col)) << 11) + s] = val;
        }
      }
    }
  }
}

// ---------------------------------------------------------------------------
// K2: fused causal attention, MFMA. Block = (h, b, 64-query tile). 4 waves,
// each owns a 16-row strip. Per 64-key step: QK^T + Q@Eband^T via MFMA,
// skew diagonal extracted with ds_bpermute, online softmax via shfl_xor,
// P->LDS(bf16)->PV MFMA against transposed V. ctx out bf16 [4096][512].
// ---------------------------------------------------------------------------
__global__ __launch_bounds__(256) void attn_kernel(
    const unsigned short* __restrict__ qh, const unsigned short* __restrict__ kh,
    const unsigned short* __restrict__ vt, const unsigned short* __restrict__ E,
    unsigned short* __restrict__ ctxo) {
  __shared__ __align__(16) short sK[64][72];
  __shared__ __align__(16) short sVT[64][72];
  __shared__ __align__(16) short sEb[128][72];
  __shared__ __align__(16) short sP[64][72];

  // heavy-first block remap for causal load balance
  const int r0 = blockIdx.x;
  int ti, hb;
  if (r0 < 256) { ti = 31 - (r0 >> 4); hb = r0 & 15; }
  else          { ti = (r0 - 256) >> 4; hb = r0 & 15; }
  const int h = hb >> 1;
  const int b = hb & 1;
  const int t0 = ti * 64;

  const int tid = threadIdx.x;
  const int w = tid >> 6;
  const int lane = tid & 63;
  const int q_ = lane >> 4;
  const int n_ = lane & 15;

  // Q A-frags for this wave's 16-row strip (held in registers for all steps)
  const int trow = t0 + 16 * w + n_;
  const unsigned short* qp = qh + (((size_t)((b << 11) + trow)) << 6) + (q_ << 3);
  const short8 qa0 = *(const short8*)qp;
  const short8 qa1 = *(const short8*)(qp + 32);

  floatx4 ctxa[4];
#pragma unroll
  for (int nb = 0; nb < 4; ++nb) ctxa[nb] = (floatx4){0.f, 0.f, 0.f, 0.f};
  float mrow[4], lrow[4];
#pragma unroll
  for (int r = 0; r < 4; ++r) { mrow[r] = -3.0e38f; lrow[r] = 0.f; }

  const unsigned short* eb = E + ((size_t)h << 17);  // h*2048*64
  const int nk = ti + 1;

  for (int kt = 0; kt < nk; ++kt) {
    const int s0 = kt * 64;
    // ---- stage K (rows s, k-major) and V^T (rows d, s-major) ----
    {
      const unsigned short* kbase = kh + (((size_t)((b << 11) + s0)) << 6);
#pragma unroll
      for (int it = 0; it < 2; ++it) {
        int idx = tid + it * 256;
        int rr = idx >> 3, cc = (idx & 7) * 8;
        *(uint4*)&sK[rr][cc] = *(const uint4*)(kbase + (rr << 6) + cc);
        *(uint4*)&sVT[rr][cc] =
            *(const uint4*)(vt + (((size_t)((b << 6) + rr)) << 11) + s0 + cc);
      }
      const int rb = (T_ - 64) + s0 - t0;  // sEb row e <-> E row rb+e
#pragma unroll
      for (int it = 0; it < 4; ++it) {
        int idx = tid + it * 256;
        int rr = idx >> 3, cc = (idx & 7) * 8;
        int gr = rb + rr; if (gr > T_ - 1) gr = T_ - 1;  // clamped rows are masked
        *(uint4*)&sEb[rr][cc] = *(const uint4*)(eb + ((size_t)gr << 6) + cc);
      }
    }
    __syncthreads();

    // ---- MFMA scores: QK (4 n-blocks) + QE (5 band-blocks for this strip) ----
    floatx4 qk[4], qe[5];
#pragma unroll
    for (int nb = 0; nb < 4; ++nb) qk[nb] = (floatx4){0.f, 0.f, 0.f, 0.f};
#pragma unroll
    for (int f = 0; f < 5; ++f) qe[f] = (floatx4){0.f, 0.f, 0.f, 0.f};
#pragma unroll
    for (int nb = 0; nb < 4; ++nb) {
      short8 b0 = *(const short8*)&sK[16 * nb + n_][8 * q_];
      short8 b1 = *(const short8*)&sK[16 * nb + n_][32 + 8 * q_];
      qk[nb] = MFMA(qa0, b0, qk[nb]);
      qk[nb] = MFMA(qa1, b1, qk[nb]);
    }
#pragma unroll
    for (int f = 0; f < 5; ++f) {
      int er = 16 * (3 - w + f) + n_;          // band rows [48-16w, 128-16w)
      short8 e0 = *(const short8*)&sEb[er][8 * q_];
      short8 e1 = *(const short8*)&sEb[er][32 + 8 * q_];
      qe[f] = MFMA(qa0, e0, qe[f]);
      qe[f] = MFMA(qa1, e1, qe[f]);
    }

    // ---- skew-diagonal gather + scale + mask ----
    // target (mb, r, lane(q_,n_)): t = 4q_+r; e = 16mb + (n_ - t + 15) + 16(3-w)
    // source frag f = mb + (n_>t), lane = q_*16 + ((n_-t+15)&15), same reg r.
    const bool diag = (s0 == t0);
#pragma unroll
    for (int r = 0; r < 4; ++r) {
      const int t = 4 * q_ + r;
      const int ba = ((q_ << 4) | ((n_ - t + 15) & 15)) << 2;
      const bool lo = (n_ <= t);
#pragma unroll
      for (int mb = 0; mb < 4; ++mb) {
        float g0 = __int_as_float(
            __builtin_amdgcn_ds_bpermute(ba, __float_as_int(qe[mb][r])));
        float g1 = __int_as_float(
            __builtin_amdgcn_ds_bpermute(ba, __float_as_int(qe[mb + 1][r])));
        float sv = (qk[mb][r] + (lo ? g0 : g1)) * 0.125f;
        if (diag && (16 * mb + n_ > 16 * w + t)) sv = -1.0e30f;
        qk[mb][r] = sv;
      }
    }

    // ---- online softmax (per row, in-register via shfl_xor over 16 lanes) ----
    float alpha[4];
#pragma unroll
    for (int r = 0; r < 4; ++r) {
      float rm = fmaxf(fmaxf(qk[0][r], qk[1][r]), fmaxf(qk[2][r], qk[3][r]));
      rm = fmaxf(rm, __shfl_xor(rm, 1));
      rm = fmaxf(rm, __shfl_xor(rm, 2));
      rm = fmaxf(rm, __shfl_xor(rm, 4));
      rm = fmaxf(rm, __shfl_xor(rm, 8));
      float mn = fmaxf(mrow[r], rm);
      alpha[r] = __expf(mrow[r] - mn);
      mrow[r] = mn;
      float rs = 0.f;
#pragma unroll
      for (int mb = 0; mb < 4; ++mb) {
        float p = __expf(qk[mb][r] - mn);
        qk[mb][r] = p;
        rs += p;
      }
      rs += __shfl_xor(rs, 1);
      rs += __shfl_xor(rs, 2);
      rs += __shfl_xor(rs, 4);
      rs += __shfl_xor(rs, 8);
      lrow[r] = lrow[r] * alpha[r] + rs;
      const int t = 4 * q_ + r;
#pragma unroll
      for (int mb = 0; mb < 4; ++mb)
        sP[16 * w + t][16 * mb + n_] = (short)f2bf(qk[mb][r]);
    }

    // ---- ctx rescale + PV MFMA (own strip's P rows only: intra-wave) ----
#pragma unroll
    for (int nb = 0; nb < 4; ++nb)
#pragma unroll
      for (int r = 0; r < 4; ++r) ctxa[nb][r] *= alpha[r];

    short8 pa0 = *(const short8*)&sP[16 * w + n_][8 * q_];
    short8 pa1 = *(const short8*)&sP[16 * w + n_][32 + 8 * q_];
#pragma unroll
    for (int nb = 0; nb < 4; ++nb) {
      short8 v0 = *(const short8*)&sVT[16 * nb + n_][8 * q_];
      short8 v1 = *(const short8*)&sVT[16 * nb + n_][32 + 8 * q_];
      ctxa[nb] = MFMA(pa0, v0, ctxa[nb]);
      ctxa[nb] = MFMA(pa1, v1, ctxa[nb]);
    }
    __syncthreads();  // protect sK/sVT/sEb restage
  }

  // ---- epilogue: ctx/l -> bf16 [4096][512] ----
#pragma unroll
  for (int r = 0; r < 4; ++r) {
    const float inv = 1.0f / lrow[r];
    const int row = t0 + 16 * w + 4 * q_ + r;
    const size_t base = (((size_t)((b << 11) + row)) << 9) + (h << 6) + n_;
#pragma unroll
    for (int nb = 0; nb < 4; ++nb)
      ctxo[base + 16 * nb] = f2bf(ctxa[nb][r] * inv);
  }
}

// ---------------------------------------------------------------------------
// K3: MFMA GEMM, A bf16 [4096][512] @ WT bf16 [Npad][512] + bias.
// RELU=1: N=512, out h1 bf16. RELU=0: N=388, out d_out (dtype per flag).
// grid (32, N/64-tiles), block 256, tile 128x64.
// ---------------------------------------------------------------------------
template <int RELU>
__global__ __launch_bounds__(256) void mlp_mfma(
    const unsigned short* __restrict__ A, const unsigned short* __restrict__ WT,
    const void* __restrict__ bias, unsigned short* __restrict__ outBF,
    void* __restrict__ outD, const int* __restrict__ flag) {
  __shared__ __align__(16) short sA[128][72];
  __shared__ __align__(16) short sW[64][72];
  const int tid = threadIdx.x;
  const int w = tid >> 6;
  const int lane = tid & 63;
  const int q_ = lane >> 4;
  const int n_ = lane & 15;
  const int row0 = blockIdx.x * 128;
  const int n0 = blockIdx.y * 64;
  const bool isbf = (*flag != 0);

  floatx4 acc[2][4];
#pragma unroll
  for (int i = 0; i < 2; ++i)
#pragma unroll
    for (int j = 0; j < 4; ++j) acc[i][j] = (floatx4){0.f, 0.f, 0.f, 0.f};

  for (int k0 = 0; k0 < DM_; k0 += 64) {
#pragma unroll
    for (int it = 0; it < 4; ++it) {
      int idx = tid + it * 256;
      int rr = idx >> 3, cc = (idx & 7) * 8;
      *(uint4*)&sA[rr][cc] =
          *(const uint4*)(A + (size_t)(row0 + rr) * DM_ + k0 + cc);
    }
#pragma unroll
    for (int it = 0; it < 2; ++it) {
      int idx = tid + it * 256;
      int rr = idx >> 3, cc = (idx & 7) * 8;
      *(uint4*)&sW[rr][cc] =
          *(const uint4*)(WT + (size_t)(n0 + rr) * DM_ + k0 + cc);
    }
    __syncthreads();

    short8 a[2][2];
#pragma unroll
    for (int mm = 0; mm < 2; ++mm) {
      a[mm][0] = *(const short8*)&sA[32 * w + 16 * mm + n_][8 * q_];
      a[mm][1] = *(const short8*)&sA[32 * w + 16 * mm + n_][32 + 8 * q_];
    }
#pragma unroll
    for (int nb = 0; nb < 4; ++nb) {
      short8 b0 = *(const short8*)&sW[16 * nb + n_][8 * q_];
      short8 b1 = *(const short8*)&sW[16 * nb + n_][32 + 8 * q_];
#pragma unroll
      for (int mm = 0; mm < 2; ++mm) {
        acc[mm][nb] = MFMA(a[mm][0], b0, acc[mm][nb]);
        acc[mm][nb] = MFMA(a[mm][1], b1, acc[mm][nb]);
      }
    }
    __syncthreads();
  }

#pragma unroll
  for (int nb = 0; nb < 4; ++nb) {
    const int col = n0 + 16 * nb + n_;
    float bb = 0.f;
    if (RELU || col < EV_) bb = ldf(bias, col, isbf);
#pragma unroll
    for (int mm = 0; mm < 2; ++mm) {
#pragma unroll
      for (int r = 0; r < 4; ++r) {
        const int row = row0 + 32 * w + 16 * mm + 4 * q_ + r;
        float v = acc[mm][nb][r] + bb;
        if (RELU) {
          outBF[(size_t)row * ED_ + col] = f2bf(fmaxf(v, 0.f));
        } else if (col < EV_) {
          if (isbf) ((unsigned short*)outD)[(size_t)row * EV_ + col] = f2bf(v);
          else      ((float*)outD)[(size_t)row * EV_ + col] = v;
        }
      }
    }
  }
}

// ---------------------------------------------------------------------------
extern "C" void kernel_launch(void* const* d_in, const int* in_sizes, int n_in,
                              void* d_out, int out_size, void* d_ws, size_t ws_size,
                              hipStream_t stream) {
  const void* v  = d_in[0];
  const void* k  = d_in[1];
  const void* q  = d_in[2];
  const void* mask = d_in[3];
  const void* Wq = d_in[4];
  const void* bq = d_in[5];
  const void* Wk = d_in[6];
  const void* bk = d_in[7];
  const void* Wv = d_in[8];
  const void* bv = d_in[9];
  const void* E  = d_in[10];
  const void* Wo = d_in[11];
  const void* bo = d_in[12];
  const void* Wl = d_in[13];
  const void* bl = d_in[14];

  char* p = (char*)d_ws;
  int* flag = (int*)p;                    p += 256;
  unsigned short* E_c  = (unsigned short*)p; p += (size_t)H_ * T_ * HD_ * 2;   // 2 MB
  unsigned short* qhb  = (unsigned short*)p; p += (size_t)BT_ * HD_ * 2;       // 512 KB
  unsigned short* khb  = (unsigned short*)p; p += (size_t)BT_ * HD_ * 2;
  unsigned short* vtb  = (unsigned short*)p; p += (size_t)BT_ * HD_ * 2;
  unsigned short* WqT  = (unsigned short*)p; p += (size_t)HD_ * DM_ * 2;       // 64 KB
  unsigned short* WkT  = (unsigned short*)p; p += (size_t)HD_ * DM_ * 2;
  unsigned short* WvT  = (unsigned short*)p; p += (size_t)HD_ * DM_ * 2;
  unsigned short* WoT  = (unsigned short*)p; p += (size_t)ED_ * DM_ * 2;       // 512 KB
  unsigned short* WlT  = (unsigned short*)p; p += (size_t)448 * DM_ * 2;       // 448 KB
  unsigned short* ctxb = (unsigned short*)p; p += (size_t)BT_ * DM_ * 2;       // 4 MB
  unsigned short* h1b  = (unsigned short*)p; p += (size_t)BT_ * ED_ * 2;       // 4 MB

  detect_kernel<<<1, 1, 0, stream>>>((const unsigned int*)mask, flag);
  convE_kernel<<<dim3(1024), 256, 0, stream>>>(E, E_c, flag);
  convT_kernel<<<dim3(1, 64), 256, 0, stream>>>(Wq, WqT, HD_, HD_, flag);
  convT_kernel<<<dim3(1, 64), 256, 0, stream>>>(Wk, WkT, HD_, HD_, flag);
  convT_kernel<<<dim3(1, 64), 256, 0, stream>>>(Wv, WvT, HD_, HD_, flag);
  convT_kernel<<<dim3(2, 64), 256, 0, stream>>>(Wo, WoT, ED_, ED_, flag);
  convT_kernel<<<dim3(2, 64), 256, 0, stream>>>(Wl, WlT, EV_, 448, flag);
  gemm_proj<<<dim3(BT_ / 128, 3), 256, 0, stream>>>(
      q, k, v, WqT, WkT, WvT, bq, bk, bv, qhb, khb, vtb, flag);
  attn_kernel<<<dim3(512), 256, 0, stream>>>(qhb, khb, vtb, E_c, ctxb);
  mlp_mfma<1><<<dim3(BT_ / 128, ED_ / 64), 256, 0, stream>>>(
      ctxb, WoT, bo, h1b, nullptr, flag);
  mlp_mfma<0><<<dim3(BT_ / 128, 448 / 64), 256, 0, stream>>>(
      h1b, WlT, bl, nullptr, d_out, flag);
}